// Round 2
// baseline (4535.006 us; speedup 1.0000x reference)
//
#include <hip/hip_runtime.h>
#include <cstdint>
#include <cstddef>
#include <cmath>

#define N_ROWS 30000
#define D_IN   784
#define NC     100
#define NCP    128
#define NSEG   12
#define SEG    30000
#define SORT_BLOCKS 118   // ceil(30000/256)

struct Hdr {
  uint32_t kperm[12][2];
  uint32_t kw[12][2];
  uint32_t kb[12][2];
  uint32_t sub[12][2][2];
  int best; int pad0;
  float bsel;
  float r2, inv_r2;
  float r1[16];
  float r1b[16];
  float R[144];      // 12x12 row-major
  float QT[120];     // 12x10
  float beta[120];   // 12x10
  float den[100];
  float num[1000];   // [c][j]
};

__device__ __forceinline__ void tf2x32(uint32_t k0, uint32_t k1,
                                       uint32_t x0, uint32_t x1,
                                       uint32_t& o0, uint32_t& o1) {
  const uint32_t kx = k0 ^ k1 ^ 0x1BD11BDAu;
  x0 += k0; x1 += k1;
  x0 += x1; x1 = (x1<<13)|(x1>>19); x1 ^= x0;
  x0 += x1; x1 = (x1<<15)|(x1>>17); x1 ^= x0;
  x0 += x1; x1 = (x1<<26)|(x1>>6);  x1 ^= x0;
  x0 += x1; x1 = (x1<<6) |(x1>>26); x1 ^= x0;
  x0 += k1; x1 += kx + 1u;
  x0 += x1; x1 = (x1<<17)|(x1>>15); x1 ^= x0;
  x0 += x1; x1 = (x1<<29)|(x1>>3);  x1 ^= x0;
  x0 += x1; x1 = (x1<<16)|(x1>>16); x1 ^= x0;
  x0 += x1; x1 = (x1<<24)|(x1>>8);  x1 ^= x0;
  x0 += kx; x1 += k0 + 2u;
  x0 += x1; x1 = (x1<<13)|(x1>>19); x1 ^= x0;
  x0 += x1; x1 = (x1<<15)|(x1>>17); x1 ^= x0;
  x0 += x1; x1 = (x1<<26)|(x1>>6);  x1 ^= x0;
  x0 += x1; x1 = (x1<<6) |(x1>>26); x1 ^= x0;
  x0 += k0; x1 += k1 + 3u;
  x0 += x1; x1 = (x1<<17)|(x1>>15); x1 ^= x0;
  x0 += x1; x1 = (x1<<29)|(x1>>3);  x1 ^= x0;
  x0 += x1; x1 = (x1<<16)|(x1>>16); x1 ^= x0;
  x0 += x1; x1 = (x1<<24)|(x1>>8);  x1 ^= x0;
  x0 += k1; x1 += kx + 4u;
  x0 += x1; x1 = (x1<<13)|(x1>>19); x1 ^= x0;
  x0 += x1; x1 = (x1<<15)|(x1>>17); x1 ^= x0;
  x0 += x1; x1 = (x1<<26)|(x1>>6);  x1 ^= x0;
  x0 += x1; x1 = (x1<<6) |(x1>>26); x1 ^= x0;
  x0 += kx; x1 += k0 + 5u;
  o0 = x0; o1 = x1;
}

__device__ __forceinline__ float u01(uint32_t bits) {
  return __uint_as_float((bits >> 9) | 0x3f800000u) - 1.0f;
}

// fold both outputs of block (0, idx) -> 32 random bits (partitionable semantics)
__device__ __forceinline__ uint32_t rbits32(uint32_t k0, uint32_t k1, uint32_t idx) {
  uint32_t o0, o1;
  tf2x32(k0, k1, 0u, idx, o0, o1);
  return o0 ^ o1;
}

// ---------------- RNG key chain (jax_threefry_partitionable=True, foldlike split) ----------------
__global__ void k_rng_chain(Hdr* h) {
  if (threadIdx.x != 0 || blockIdx.x != 0) return;
  uint32_t c0 = 0u, c1 = 42u;  // jax.random.key(42) -> [0,42]
  for (int k = 0; k < 12; k++) {
    uint32_t t0, t1;
    // split(key,4): row i = both outputs of block (x0=0, x1=i); row0=new key
    tf2x32(c0, c1, 0u, 1u, t0, t1); h->kperm[k][0] = t0; h->kperm[k][1] = t1;
    tf2x32(c0, c1, 0u, 2u, t0, t1); h->kw[k][0]   = t0; h->kw[k][1]   = t1;
    tf2x32(c0, c1, 0u, 3u, t0, t1); h->kb[k][0]   = t0; h->kb[k][1]   = t1;
    uint32_t p0 = h->kperm[k][0], p1 = h->kperm[k][1];
    for (int r = 0; r < 2; r++) {   // _shuffle: key,subkey = split(key) per round
      uint32_t s0, s1, n0, n1;
      tf2x32(p0, p1, 0u, 1u, s0, s1);   // subkey = row1
      tf2x32(p0, p1, 0u, 0u, n0, n1);   // new key = row0
      h->sub[k][r][0] = s0; h->sub[k][r][1] = s1;
      p0 = n0; p1 = n1;
    }
    tf2x32(c0, c1, 0u, 0u, t0, t1); c0 = t0; c1 = t1;  // carried key = row0
  }
}

// ---------------- sort key generation ----------------
__global__ __launch_bounds__(256) void k_sortkeys(const Hdr* __restrict__ h,
    uint32_t* __restrict__ keys, int* __restrict__ vals, int round) {
  int p = blockIdx.x * 256 + threadIdx.x;
  if (p >= NSEG * SEG) return;
  int s = p / SEG, i = p % SEG;
  keys[p] = rbits32(h->sub[s][round][0], h->sub[s][round][1], (uint32_t)i);
  if (round == 0) vals[p] = i;
}

// ---------------- stable LSD radix sort (8-bit digits) ----------------
__global__ __launch_bounds__(256) void k_hist(const uint32_t* __restrict__ keys,
    uint32_t* __restrict__ hs, int shift) {
  __shared__ uint32_t hloc[256];
  int s = blockIdx.x / SORT_BLOCKS, b = blockIdx.x % SORT_BLOCKS;
  hloc[threadIdx.x] = 0;
  __syncthreads();
  int i = b * 256 + threadIdx.x;
  if (i < SEG) {
    uint32_t d = (keys[s * SEG + i] >> shift) & 255u;
    atomicAdd(&hloc[d], 1u);
  }
  __syncthreads();
  hs[(size_t)(s * SORT_BLOCKS + b) * 256 + threadIdx.x] = hloc[threadIdx.x];
}

__global__ __launch_bounds__(256) void k_scan(uint32_t* hs) {
  __shared__ uint32_t tot[256];
  __shared__ uint32_t base[256];
  int s = blockIdx.x, d = threadIdx.x;
  uint32_t run = 0;
  for (int b = 0; b < SORT_BLOCKS; b++) {
    size_t idx = (size_t)(s * SORT_BLOCKS + b) * 256 + d;
    uint32_t c = hs[idx];
    hs[idx] = run;
    run += c;
  }
  tot[d] = run;
  __syncthreads();
  if (d == 0) {
    uint32_t acc = 0;
    for (int q = 0; q < 256; q++) { base[q] = acc; acc += tot[q]; }
  }
  __syncthreads();
  uint32_t bb = base[d];
  for (int b = 0; b < SORT_BLOCKS; b++)
    hs[(size_t)(s * SORT_BLOCKS + b) * 256 + d] += bb;
}

__global__ __launch_bounds__(256) void k_scatter(const uint32_t* __restrict__ ik,
    const int* __restrict__ iv, uint32_t* __restrict__ ok, int* __restrict__ ov,
    const uint32_t* __restrict__ hs, int shift) {
  __shared__ uint16_t wh[4][256];
  int s = blockIdx.x / SORT_BLOCKS, b = blockIdx.x % SORT_BLOCKS;
  int tid = threadIdx.x;
  for (int q = tid; q < 1024; q += 256) ((uint16_t*)wh)[q] = 0;
  __syncthreads();
  int i = b * 256 + tid;
  bool valid = (i < SEG);
  uint32_t key = 0, dg = 0; int val = 0;
  if (valid) {
    key = ik[s * SEG + i];
    val = iv[s * SEG + i];
    dg = (key >> shift) & 255u;
  }
  unsigned long long vm = __ballot(valid ? 1 : 0);
  unsigned long long m = ~0ULL;
  for (int bit = 0; bit < 8; bit++) {
    unsigned long long bm = __ballot((int)((dg >> bit) & 1u));
    m &= ((dg >> bit) & 1u) ? bm : ~bm;
  }
  m &= vm;
  int wv = tid >> 6, lane = tid & 63;
  int rw = __popcll(m & ((1ULL << lane) - 1ULL));
  if (valid && rw == 0) wh[wv][dg] = (uint16_t)__popcll(m);
  __syncthreads();
  if (valid) {
    int rank = rw;
    for (int q = 0; q < wv; q++) rank += wh[q][dg];
    uint32_t pos = hs[(size_t)(s * SORT_BLOCKS + b) * 256 + dg] + rank;
    ok[s * SEG + pos] = key;
    ov[s * SEG + pos] = val;
  }
}

// ---------------- candidate weight generation ----------------
__global__ __launch_bounds__(256) void k_genw(const Hdr* __restrict__ h, float* __restrict__ Wr) {
  int t = blockIdx.x * 256 + threadIdx.x;
  if (t >= NSEG * D_IN * NCP) return;
  int k = t / (D_IN * NCP);
  int rem = t % (D_IN * NCP);
  int d = rem / NCP, c = rem % NCP;
  float val = 0.f;
  if (c < NC) {
    int n = d * NC + c;          // row-major linear index of (784,100)
    float u = u01(rbits32(h->kw[k][0], h->kw[k][1], (uint32_t)n));
    float lam = (c < 50) ? 1.f : 10.f;
    val = lam * (2.f * u - 1.f);
  }
  Wr[t] = val;
}

__global__ __launch_bounds__(256) void k_genb(const Hdr* __restrict__ h, float* __restrict__ br) {
  int t = blockIdx.x * 256 + threadIdx.x;
  if (t >= NSEG * NC) return;
  int k = t / NC, c = t % NC;
  float u = u01(rbits32(h->kb[k][0], h->kb[k][1], (uint32_t)c));
  float lam = (c < 50) ? 1.f : 10.f;
  br[t] = lam * (2.f * u - 1.f);
}

// ---------------- per-iteration kernels ----------------
__global__ __launch_bounds__(256) void k_ek(const float* __restrict__ Y,
    const float* __restrict__ y, const int* __restrict__ perm,
    float* __restrict__ ek, Hdr* h, int k, int bs) {
  if (blockIdx.x == 0 && threadIdx.x < 16) { h->r1[threadIdx.x] = 0.f; h->r1b[threadIdx.x] = 0.f; }
  int i = blockIdx.x * 256 + threadIdx.x;
  if (i >= bs) return;
  int idx = perm[i];
  #pragma unroll
  for (int j = 0; j < 10; j++) {
    float e = Y[(size_t)idx * 10 + j];
    if (k > 0) e -= y[(size_t)idx * 10 + j];
    ek[(size_t)i * 10 + j] = e;
  }
}

#define TR 32
__global__ __launch_bounds__(256) void k_batch_h(const float* __restrict__ X,
    const float* __restrict__ Wr, const float* __restrict__ br,
    const int* __restrict__ perm, float* __restrict__ hbuf, int bs) {
  __shared__ __align__(16) float Xs[TR][64];
  __shared__ __align__(16) float Ws[64][NCP];
  __shared__ int idxs[TR];
  int tid = threadIdx.x;
  int row0 = blockIdx.x * TR;
  if (tid < TR) {
    int r = row0 + tid;
    idxs[tid] = perm[r < bs ? r : (bs - 1)];
  }
  __syncthreads();
  int cg = tid & 31;      // c0 = cg*4
  int rg = tid >> 5;      // 0..7 ; rows rg+8a
  int c0 = cg * 4;
  float acc[4][4];
  #pragma unroll
  for (int a = 0; a < 4; a++)
    #pragma unroll
    for (int b = 0; b < 4; b++) acc[a][b] = 0.f;
  int lr = tid >> 3;          // 0..31
  int ld = (tid & 7) * 8;     // 0..56
  for (int d0 = 0; d0 < D_IN; d0 += 64) {
    const float* xp = X + (size_t)idxs[lr] * D_IN + d0 + ld;
    #pragma unroll
    for (int q = 0; q < 8; q++) {
      int dd = d0 + ld + q;
      Xs[lr][ld + q] = (dd < D_IN) ? xp[q] : 0.f;
    }
    #pragma unroll
    for (int mm = 0; mm < 32; mm++) {
      int lin = tid + 256 * mm;
      int dk = lin >> 7, c = lin & 127;
      int dd = d0 + dk;
      Ws[dk][c] = (dd < D_IN) ? Wr[(size_t)dd * NCP + c] : 0.f;
    }
    __syncthreads();
    #pragma unroll 4
    for (int dk = 0; dk < 64; dk++) {
      float4 wv = *(const float4*)&Ws[dk][c0];
      float x0 = Xs[rg][dk], x1 = Xs[rg + 8][dk], x2 = Xs[rg + 16][dk], x3 = Xs[rg + 24][dk];
      acc[0][0] += x0 * wv.x; acc[0][1] += x0 * wv.y; acc[0][2] += x0 * wv.z; acc[0][3] += x0 * wv.w;
      acc[1][0] += x1 * wv.x; acc[1][1] += x1 * wv.y; acc[1][2] += x1 * wv.z; acc[1][3] += x1 * wv.w;
      acc[2][0] += x2 * wv.x; acc[2][1] += x2 * wv.y; acc[2][2] += x2 * wv.z; acc[2][3] += x2 * wv.w;
      acc[3][0] += x3 * wv.x; acc[3][1] += x3 * wv.y; acc[3][2] += x3 * wv.z; acc[3][3] += x3 * wv.w;
    }
    __syncthreads();
  }
  if (c0 < NC) {
    #pragma unroll
    for (int a = 0; a < 4; a++) {
      int row = row0 + rg + 8 * a;
      if (row < bs) {
        #pragma unroll
        for (int q = 0; q < 4; q++) {
          float z = acc[a][q] + br[c0 + q];
          hbuf[(size_t)row * NCP + c0 + q] = 1.f / (1.f + expf(-z));
        }
      }
    }
  }
}

__global__ __launch_bounds__(256) void k_reduce_v(const float* __restrict__ hbuf,
    const float* __restrict__ ek, Hdr* h, int bs) {
  int c = blockIdx.x;
  int tid = threadIdx.x;
  float den = 0.f, num[10];
  #pragma unroll
  for (int j = 0; j < 10; j++) num[j] = 0.f;
  for (int i = tid; i < bs; i += 256) {
    float hv = hbuf[(size_t)i * NCP + c];
    den += hv * hv;
    const float* e = ek + (size_t)i * 10;
    #pragma unroll
    for (int j = 0; j < 10; j++) num[j] += hv * e[j];
  }
  __shared__ float red[256][11];
  red[tid][0] = den;
  #pragma unroll
  for (int j = 0; j < 10; j++) red[tid][1 + j] = num[j];
  __syncthreads();
  for (int s = 128; s > 0; s >>= 1) {
    if (tid < s) {
      #pragma unroll
      for (int q = 0; q < 11; q++) red[tid][q] += red[tid + s][q];
    }
    __syncthreads();
  }
  if (tid == 0) {
    h->den[c] = red[0][0];
    #pragma unroll
    for (int j = 0; j < 10; j++) h->num[c * 10 + j] = red[0][1 + j];
  }
}

__global__ void k_select(Hdr* h, const float* __restrict__ br, float* __restrict__ out_b, int k) {
  if (threadIdx.x != 0 || blockIdx.x != 0) return;
  float best = -1.f; int bi = 0;
  for (int c = 0; c < NC; c++) {
    float s = 0.f;
    for (int j = 0; j < 10; j++) { float n = h->num[c * 10 + j]; s += n * n; }
    float v = s / (h->den[c] * 10.f);
    if (v > best) { best = v; bi = c; }
  }
  h->best = bi;
  h->bsel = br[k * NC + bi];
  out_b[k] = h->bsel;
}

__global__ __launch_bounds__(256) void k_wcol(const Hdr* __restrict__ h,
    const float* __restrict__ Wr, float* __restrict__ wcol, float* __restrict__ outW, int k) {
  int d = blockIdx.x * 256 + threadIdx.x;
  if (d >= D_IN) return;
  float v = Wr[(size_t)d * NCP + h->best];
  wcol[d] = v;
  outW[d * 12 + k] = v;
}

__global__ __launch_bounds__(256) void k_hc(const float* __restrict__ X,
    const Hdr* __restrict__ h, const float* __restrict__ wcol,
    float* __restrict__ H, float* __restrict__ hc, int k) {
  int lane = threadIdx.x & 63;
  int row = blockIdx.x * 4 + (threadIdx.x >> 6);
  if (row >= N_ROWS) return;
  const float* xp = X + (size_t)row * D_IN;
  float acc = 0.f;
  for (int d = lane; d < D_IN; d += 64) acc += xp[d] * wcol[d];
  for (int o = 32; o > 0; o >>= 1) acc += __shfl_down(acc, o, 64);
  if (lane == 0) {
    float hv = 1.f / (1.f + expf(-(acc + h->bsel)));
    H[(size_t)row * 12 + k] = hv;
    hc[row] = hv;
  }
}

__global__ __launch_bounds__(256) void k_dotQ(const float* __restrict__ Qcm,
    const float* __restrict__ vec, float* __restrict__ dst) {
  int j = blockIdx.x;
  const float* q = Qcm + (size_t)j * N_ROWS;
  float a = 0.f;
  for (int i = threadIdx.x; i < N_ROWS; i += 256) a += q[i] * vec[i];
  __shared__ float red[256];
  red[threadIdx.x] = a;
  __syncthreads();
  for (int s = 128; s > 0; s >>= 1) {
    if (threadIdx.x < s) red[threadIdx.x] += red[threadIdx.x + s];
    __syncthreads();
  }
  if (threadIdx.x == 0) dst[j] = red[0];
}

__global__ __launch_bounds__(256) void k_sub(float* __restrict__ Qcm,
    const float* __restrict__ basev, const float* __restrict__ coef,
    float* __restrict__ partials, int k) {
  int i = blockIdx.x * 256 + threadIdx.x;
  float t = 0.f;
  if (i < N_ROWS) {
    t = basev[i];
    for (int j = 0; j < k; j++) t -= Qcm[(size_t)j * N_ROWS + i] * coef[j];
    Qcm[(size_t)k * N_ROWS + i] = t;
  }
  __shared__ float red[256];
  red[threadIdx.x] = t * t;
  __syncthreads();
  for (int s = 128; s > 0; s >>= 1) {
    if (threadIdx.x < s) red[threadIdx.x] += red[threadIdx.x + s];
    __syncthreads();
  }
  if (threadIdx.x == 0) partials[blockIdx.x] = red[0];
}

__global__ void k_r2(Hdr* h, const float* __restrict__ partials, int k) {
  int tid = threadIdx.x;
  if (tid == 0) {
    float s = 0.f;
    for (int b = 0; b < SORT_BLOCKS; b++) s += partials[b];
    float r2 = sqrtf(s);
    h->r2 = r2;
    h->inv_r2 = 1.f / r2;
    h->R[k * 12 + k] = r2;
  }
  if (tid < k) h->R[tid * 12 + k] = h->r1[tid] + h->r1b[tid];
}

__global__ __launch_bounds__(256) void k_qt(Hdr* h, const float* __restrict__ Qk,
    const float* __restrict__ Y, int k) {
  int j = blockIdx.x;
  float a = 0.f;
  for (int i = threadIdx.x; i < N_ROWS; i += 256) a += Qk[i] * Y[(size_t)i * 10 + j];
  __shared__ float red[256];
  red[threadIdx.x] = a;
  __syncthreads();
  for (int s = 128; s > 0; s >>= 1) {
    if (threadIdx.x < s) red[threadIdx.x] += red[threadIdx.x + s];
    __syncthreads();
  }
  if (threadIdx.x == 0) h->QT[k * 10 + j] = red[0] * h->inv_r2;
}

__global__ __launch_bounds__(256) void k_qnorm(float* __restrict__ Qk, const Hdr* __restrict__ h) {
  int i = blockIdx.x * 256 + threadIdx.x;
  if (i < N_ROWS) Qk[i] *= h->inv_r2;
}

__global__ void k_backsub(Hdr* h, float* __restrict__ out_beta, int k) {
  int j = threadIdx.x;
  if (j >= 10 || blockIdx.x != 0) return;
  for (int i = k; i >= 0; i--) {
    float t = h->QT[i * 10 + j];
    for (int m = i + 1; m <= k; m++) t -= h->R[i * 12 + m] * h->beta[m * 10 + j];
    t /= h->R[i * 12 + i];
    h->beta[i * 10 + j] = t;
    out_beta[i * 10 + j] = t;
  }
}

__global__ __launch_bounds__(256) void k_y(const Hdr* __restrict__ h,
    const float* __restrict__ H, float* __restrict__ y, int k) {
  __shared__ float sb[120];
  if (threadIdx.x < 120) sb[threadIdx.x] = h->beta[threadIdx.x];
  __syncthreads();
  int i = blockIdx.x * 256 + threadIdx.x;
  if (i >= N_ROWS) return;
  float hr[12];
  for (int m = 0; m <= k; m++) hr[m] = H[(size_t)i * 12 + m];
  #pragma unroll
  for (int j = 0; j < 10; j++) {
    float a = 0.f;
    for (int m = 0; m <= k; m++) a += hr[m] * sb[m * 10 + j];
    y[(size_t)i * 10 + j] = a;
  }
}

static inline int cdiv(int a, int b) { return (a + b - 1) / b; }

extern "C" void kernel_launch(void* const* d_in, const int* in_sizes, int n_in,
                              void* d_out, int out_size, void* d_ws, size_t ws_size,
                              hipStream_t stream) {
  const float* X = (const float*)d_in[0];
  const float* Y = (const float*)d_in[1];
  float* out = (float*)d_out;
  float* outW = out;             // 784*12
  float* outB = out + 9408;      // 12
  float* outBeta = out + 9420;   // 12*10

  char* base = (char*)d_ws;
  Hdr* hdr = (Hdr*)base;
  float* r1p  = (float*)(base + offsetof(Hdr, r1));
  float* r1bp = (float*)(base + offsetof(Hdr, r1b));

  size_t off = 16384;
  auto nxt = [&](size_t bytes) -> void* {
    void* p = base + off;
    off += (bytes + 255) & ~(size_t)255;
    return p;
  };
  uint32_t* keysA = (uint32_t*)nxt((size_t)NSEG * SEG * 4);
  uint32_t* keysB = (uint32_t*)nxt((size_t)NSEG * SEG * 4);
  int* valsA = (int*)nxt((size_t)NSEG * SEG * 4);
  int* valsB = (int*)nxt((size_t)NSEG * SEG * 4);
  uint32_t* hs = (uint32_t*)nxt((size_t)NSEG * SORT_BLOCKS * 256 * 4);
  float* WrAll = (float*)nxt((size_t)NSEG * D_IN * NCP * 4);
  float* brAll = (float*)nxt((size_t)NSEG * NC * 4);
  float* wcol = (float*)nxt((size_t)D_IN * 4);
  float* hbuf = (float*)nxt((size_t)27840 * NCP * 4);
  float* ekbuf = (float*)nxt((size_t)27840 * 10 * 4);
  float* Qcm = (float*)nxt((size_t)12 * N_ROWS * 4);
  float* Hbuf = (float*)nxt((size_t)N_ROWS * 12 * 4);
  float* hcbuf = (float*)nxt((size_t)N_ROWS * 4);
  float* ybuf = (float*)nxt((size_t)N_ROWS * 10 * 4);
  float* partials = (float*)nxt(128 * 4);

  // 1. RNG key chain
  k_rng_chain<<<1, 64, 0, stream>>>(hdr);

  // 2. permutations: round 1 keys + iota values, 4 radix passes; round 2; 4 passes.
  const int keygrid = cdiv(NSEG * SEG, 256);
  const int sortgrid = NSEG * SORT_BLOCKS;
  k_sortkeys<<<keygrid, 256, 0, stream>>>(hdr, keysA, valsA, 0);
  for (int pass = 0; pass < 4; pass++) {
    uint32_t* ik = (pass & 1) ? keysB : keysA;
    uint32_t* ok = (pass & 1) ? keysA : keysB;
    int* iv = (pass & 1) ? valsB : valsA;
    int* ov = (pass & 1) ? valsA : valsB;
    k_hist<<<sortgrid, 256, 0, stream>>>(ik, hs, 8 * pass);
    k_scan<<<NSEG, 256, 0, stream>>>(hs);
    k_scatter<<<sortgrid, 256, 0, stream>>>(ik, iv, ok, ov, hs, 8 * pass);
  }
  k_sortkeys<<<keygrid, 256, 0, stream>>>(hdr, keysA, valsA, 1);
  for (int pass = 0; pass < 4; pass++) {
    uint32_t* ik = (pass & 1) ? keysB : keysA;
    uint32_t* ok = (pass & 1) ? keysA : keysB;
    int* iv = (pass & 1) ? valsB : valsA;
    int* ov = (pass & 1) ? valsA : valsB;
    k_hist<<<sortgrid, 256, 0, stream>>>(ik, hs, 8 * pass);
    k_scan<<<NSEG, 256, 0, stream>>>(hs);
    k_scatter<<<sortgrid, 256, 0, stream>>>(ik, iv, ok, ov, hs, 8 * pass);
  }

  // 3. candidate weights
  k_genw<<<cdiv(NSEG * D_IN * NCP, 256), 256, 0, stream>>>(hdr, WrAll);
  k_genb<<<cdiv(NSEG * NC, 256), 256, 0, stream>>>(hdr, brAll);

  // 4. sequential training loop
  for (int k = 0; k < 12; k++) {
    int bs = 4000 + 2166 * k;
    const int* perm = valsA + (size_t)k * SEG;
    const float* Wrk = WrAll + (size_t)k * D_IN * NCP;
    const float* brk = brAll + (size_t)k * NC;

    k_ek<<<cdiv(bs, 256), 256, 0, stream>>>(Y, ybuf, perm, ekbuf, hdr, k, bs);
    k_batch_h<<<cdiv(bs, TR), 256, 0, stream>>>(X, Wrk, brk, perm, hbuf, bs);
    k_reduce_v<<<NC, 256, 0, stream>>>(hbuf, ekbuf, hdr, bs);
    k_select<<<1, 64, 0, stream>>>(hdr, brAll, outB, k);
    k_wcol<<<cdiv(D_IN, 256), 256, 0, stream>>>(hdr, Wrk, wcol, outW, k);
    k_hc<<<N_ROWS / 4, 256, 0, stream>>>(X, hdr, wcol, Hbuf, hcbuf, k);

    if (k > 0) k_dotQ<<<k, 256, 0, stream>>>(Qcm, hcbuf, r1p);
    k_sub<<<SORT_BLOCKS, 256, 0, stream>>>(Qcm, hcbuf, r1p, partials, k);
    if (k == 1 || k == 2) {  // reorthogonalize (emulates inv/Householder branches)
      k_dotQ<<<k, 256, 0, stream>>>(Qcm, Qcm + (size_t)k * N_ROWS, r1bp);
      k_sub<<<SORT_BLOCKS, 256, 0, stream>>>(Qcm, Qcm + (size_t)k * N_ROWS, r1bp, partials, k);
    }
    k_r2<<<1, 64, 0, stream>>>(hdr, partials, k);
    k_qt<<<10, 256, 0, stream>>>(hdr, Qcm + (size_t)k * N_ROWS, Y, k);
    k_qnorm<<<SORT_BLOCKS, 256, 0, stream>>>(Qcm + (size_t)k * N_ROWS, hdr);
    k_backsub<<<1, 64, 0, stream>>>(hdr, outBeta, k);
    k_y<<<SORT_BLOCKS, 256, 0, stream>>>(hdr, Hbuf, ybuf, k);
  }
}

// Round 3
// 3117.709 us; speedup vs baseline: 1.4546x; 1.4546x over previous
//
#include <hip/hip_runtime.h>
#include <cstdint>
#include <cstddef>
#include <cmath>

#define N_ROWS 30000
#define D_IN   784
#define NC     100
#define NCP    128
#define NSEG   12
#define SEG    30000
#define SORT_BLOCKS 118   // ceil(30000/256)
#define KP     800        // K padded to multiple of 32

typedef short bf16x8 __attribute__((ext_vector_type(8)));
typedef float f32x4  __attribute__((ext_vector_type(4)));

struct Hdr {
  uint32_t kperm[12][2];
  uint32_t kw[12][2];
  uint32_t kb[12][2];
  uint32_t sub[12][2][2];
  int best; int pad0;
  float bsel;
  float r2, inv_r2;
  float r1[16];
  float r1b[16];
  float R[144];      // 12x12 row-major
  float QT[120];     // 12x10
  float beta[120];   // 12x10
  float den[100];
  float num[1000];   // [c][j]
};

__device__ __forceinline__ void tf2x32(uint32_t k0, uint32_t k1,
                                       uint32_t x0, uint32_t x1,
                                       uint32_t& o0, uint32_t& o1) {
  const uint32_t kx = k0 ^ k1 ^ 0x1BD11BDAu;
  x0 += k0; x1 += k1;
  x0 += x1; x1 = (x1<<13)|(x1>>19); x1 ^= x0;
  x0 += x1; x1 = (x1<<15)|(x1>>17); x1 ^= x0;
  x0 += x1; x1 = (x1<<26)|(x1>>6);  x1 ^= x0;
  x0 += x1; x1 = (x1<<6) |(x1>>26); x1 ^= x0;
  x0 += k1; x1 += kx + 1u;
  x0 += x1; x1 = (x1<<17)|(x1>>15); x1 ^= x0;
  x0 += x1; x1 = (x1<<29)|(x1>>3);  x1 ^= x0;
  x0 += x1; x1 = (x1<<16)|(x1>>16); x1 ^= x0;
  x0 += x1; x1 = (x1<<24)|(x1>>8);  x1 ^= x0;
  x0 += kx; x1 += k0 + 2u;
  x0 += x1; x1 = (x1<<13)|(x1>>19); x1 ^= x0;
  x0 += x1; x1 = (x1<<15)|(x1>>17); x1 ^= x0;
  x0 += x1; x1 = (x1<<26)|(x1>>6);  x1 ^= x0;
  x0 += x1; x1 = (x1<<6) |(x1>>26); x1 ^= x0;
  x0 += k0; x1 += k1 + 3u;
  x0 += x1; x1 = (x1<<17)|(x1>>15); x1 ^= x0;
  x0 += x1; x1 = (x1<<29)|(x1>>3);  x1 ^= x0;
  x0 += x1; x1 = (x1<<16)|(x1>>16); x1 ^= x0;
  x0 += x1; x1 = (x1<<24)|(x1>>8);  x1 ^= x0;
  x0 += k1; x1 += kx + 4u;
  x0 += x1; x1 = (x1<<13)|(x1>>19); x1 ^= x0;
  x0 += x1; x1 = (x1<<15)|(x1>>17); x1 ^= x0;
  x0 += x1; x1 = (x1<<26)|(x1>>6);  x1 ^= x0;
  x0 += x1; x1 = (x1<<6) |(x1>>26); x1 ^= x0;
  x0 += kx; x1 += k0 + 5u;
  o0 = x0; o1 = x1;
}

__device__ __forceinline__ float u01(uint32_t bits) {
  return __uint_as_float((bits >> 9) | 0x3f800000u) - 1.0f;
}

__device__ __forceinline__ uint32_t rbits32(uint32_t k0, uint32_t k1, uint32_t idx) {
  uint32_t o0, o1;
  tf2x32(k0, k1, 0u, idx, o0, o1);
  return o0 ^ o1;
}

__device__ __forceinline__ ushort f2bf_rne(float f) {
  uint32_t u = __float_as_uint(f);
  return (ushort)((u + 0x7fffu + ((u >> 16) & 1u)) >> 16);
}
__device__ __forceinline__ float bf2f(ushort h) {
  return __uint_as_float(((uint32_t)h) << 16);
}

// ---------------- RNG key chain (jax_threefry_partitionable=True) ----------------
__global__ void k_rng_chain(Hdr* h) {
  if (threadIdx.x != 0 || blockIdx.x != 0) return;
  uint32_t c0 = 0u, c1 = 42u;
  for (int k = 0; k < 12; k++) {
    uint32_t t0, t1;
    tf2x32(c0, c1, 0u, 1u, t0, t1); h->kperm[k][0] = t0; h->kperm[k][1] = t1;
    tf2x32(c0, c1, 0u, 2u, t0, t1); h->kw[k][0]   = t0; h->kw[k][1]   = t1;
    tf2x32(c0, c1, 0u, 3u, t0, t1); h->kb[k][0]   = t0; h->kb[k][1]   = t1;
    uint32_t p0 = h->kperm[k][0], p1 = h->kperm[k][1];
    for (int r = 0; r < 2; r++) {
      uint32_t s0, s1, n0, n1;
      tf2x32(p0, p1, 0u, 1u, s0, s1);
      tf2x32(p0, p1, 0u, 0u, n0, n1);
      h->sub[k][r][0] = s0; h->sub[k][r][1] = s1;
      p0 = n0; p1 = n1;
    }
    tf2x32(c0, c1, 0u, 0u, t0, t1); c0 = t0; c1 = t1;
  }
}

// ---------------- sort key generation ----------------
__global__ __launch_bounds__(256) void k_sortkeys(const Hdr* __restrict__ h,
    uint32_t* __restrict__ keys, int* __restrict__ vals, int round) {
  int p = blockIdx.x * 256 + threadIdx.x;
  if (p >= NSEG * SEG) return;
  int s = p / SEG, i = p % SEG;
  keys[p] = rbits32(h->sub[s][round][0], h->sub[s][round][1], (uint32_t)i);
  if (round == 0) vals[p] = i;
}

// ---------------- stable LSD radix sort (8-bit digits) ----------------
__global__ __launch_bounds__(256) void k_hist(const uint32_t* __restrict__ keys,
    uint32_t* __restrict__ hs, int shift) {
  __shared__ uint32_t hloc[256];
  int s = blockIdx.x / SORT_BLOCKS, b = blockIdx.x % SORT_BLOCKS;
  hloc[threadIdx.x] = 0;
  __syncthreads();
  int i = b * 256 + threadIdx.x;
  if (i < SEG) {
    uint32_t d = (keys[s * SEG + i] >> shift) & 255u;
    atomicAdd(&hloc[d], 1u);
  }
  __syncthreads();
  hs[(size_t)(s * SORT_BLOCKS + b) * 256 + threadIdx.x] = hloc[threadIdx.x];
}

__global__ __launch_bounds__(256) void k_scan(uint32_t* hs) {
  __shared__ uint32_t tot[256];
  __shared__ uint32_t base[256];
  int s = blockIdx.x, d = threadIdx.x;
  uint32_t run = 0;
  for (int b = 0; b < SORT_BLOCKS; b++) {
    size_t idx = (size_t)(s * SORT_BLOCKS + b) * 256 + d;
    uint32_t c = hs[idx];
    hs[idx] = run;
    run += c;
  }
  tot[d] = run;
  __syncthreads();
  if (d == 0) {
    uint32_t acc = 0;
    for (int q = 0; q < 256; q++) { base[q] = acc; acc += tot[q]; }
  }
  __syncthreads();
  uint32_t bb = base[d];
  for (int b = 0; b < SORT_BLOCKS; b++)
    hs[(size_t)(s * SORT_BLOCKS + b) * 256 + d] += bb;
}

__global__ __launch_bounds__(256) void k_scatter(const uint32_t* __restrict__ ik,
    const int* __restrict__ iv, uint32_t* __restrict__ ok, int* __restrict__ ov,
    const uint32_t* __restrict__ hs, int shift) {
  __shared__ uint16_t wh[4][256];
  int s = blockIdx.x / SORT_BLOCKS, b = blockIdx.x % SORT_BLOCKS;
  int tid = threadIdx.x;
  for (int q = tid; q < 1024; q += 256) ((uint16_t*)wh)[q] = 0;
  __syncthreads();
  int i = b * 256 + tid;
  bool valid = (i < SEG);
  uint32_t key = 0, dg = 0; int val = 0;
  if (valid) {
    key = ik[s * SEG + i];
    val = iv[s * SEG + i];
    dg = (key >> shift) & 255u;
  }
  unsigned long long vm = __ballot(valid ? 1 : 0);
  unsigned long long m = ~0ULL;
  for (int bit = 0; bit < 8; bit++) {
    unsigned long long bm = __ballot((int)((dg >> bit) & 1u));
    m &= ((dg >> bit) & 1u) ? bm : ~bm;
  }
  m &= vm;
  int wv = tid >> 6, lane = tid & 63;
  int rw = __popcll(m & ((1ULL << lane) - 1ULL));
  if (valid && rw == 0) wh[wv][dg] = (uint16_t)__popcll(m);
  __syncthreads();
  if (valid) {
    int rank = rw;
    for (int q = 0; q < wv; q++) rank += wh[q][dg];
    uint32_t pos = hs[(size_t)(s * SORT_BLOCKS + b) * 256 + dg] + rank;
    ok[s * SEG + pos] = key;
    ov[s * SEG + pos] = val;
  }
}

// ---------------- candidate weight generation ----------------
// Writes: Wr fp32 [seg][d<784][c<128] (exact output path),
//         Wthi/Wtlo bf16 transposed [seg][c<128][k<800] zero-padded (MFMA B path)
__global__ __launch_bounds__(256) void k_gen(const Hdr* __restrict__ h,
    float* __restrict__ Wr, short* __restrict__ Wthi, short* __restrict__ Wtlo) {
  int t = blockIdx.x * 256 + threadIdx.x;
  if (t >= NSEG * NCP * KP) return;
  int seg = t / (NCP * KP);
  int r = t % (NCP * KP);
  int c = r / KP, d = r % KP;
  float val = 0.f;
  if (c < NC && d < D_IN) {
    int n = d * NC + c;  // row-major linear index of (784,100)
    float u = u01(rbits32(h->kw[seg][0], h->kw[seg][1], (uint32_t)n));
    float lam = (c < 50) ? 1.f : 10.f;
    val = lam * (2.f * u - 1.f);
  }
  ushort hi = f2bf_rne(val);
  ushort lo = f2bf_rne(val - bf2f(hi));
  Wthi[t] = (short)hi;
  Wtlo[t] = (short)lo;
  if (d < D_IN) Wr[(size_t)seg * D_IN * NCP + (size_t)d * NCP + c] = val;
}

__global__ __launch_bounds__(256) void k_genb(const Hdr* __restrict__ h, float* __restrict__ br) {
  int t = blockIdx.x * 256 + threadIdx.x;
  if (t >= NSEG * NC) return;
  int k = t / NC, c = t % NC;
  float u = u01(rbits32(h->kb[k][0], h->kb[k][1], (uint32_t)c));
  float lam = (c < 50) ? 1.f : 10.f;
  br[t] = lam * (2.f * u - 1.f);
}

// ---------------- per-iteration kernels ----------------
__global__ __launch_bounds__(256) void k_ek(const float* __restrict__ Y,
    const float* __restrict__ y, const int* __restrict__ perm,
    float* __restrict__ ek, Hdr* h, int k, int bs) {
  if (blockIdx.x == 0 && threadIdx.x < 16) { h->r1[threadIdx.x] = 0.f; h->r1b[threadIdx.x] = 0.f; }
  int i = blockIdx.x * 256 + threadIdx.x;
  if (i >= bs) return;
  int idx = perm[i];
  #pragma unroll
  for (int j = 0; j < 10; j++) {
    float e = Y[(size_t)idx * 10 + j];
    if (k > 0) e -= y[(size_t)idx * 10 + j];
    ek[(size_t)i * 10 + j] = e;
  }
}

// ---- MFMA split-bf16 candidate GEMM: hbuf[bs rows][128] = sigmoid(Xk @ W + b) ----
// block: 64 gathered rows x 128 cols; 4 waves, wave w owns n-tiles {2w,2w+1}, m-tiles 0..3
__global__ __launch_bounds__(256) void k_batch_mfma(const float* __restrict__ X,
    const short* __restrict__ Wthi, const short* __restrict__ Wtlo,
    const float* __restrict__ br, const int* __restrict__ perm,
    float* __restrict__ hbuf, int bs) {
  __shared__ short Ah[64][40], Al[64][40];    // 80B row stride: conflict-free b128
  __shared__ short Bh[128][40], Bl[128][40];
  __shared__ int idxs[64];
  int tid = threadIdx.x;
  int row0 = blockIdx.x * 64;
  if (tid < 64) {
    int rr = row0 + tid;
    idxs[tid] = perm[rr < bs ? rr : (bs - 1)];
  }
  int wave = tid >> 6, lane = tid & 63;
  int kg = lane >> 4, ln = lane & 15;

  f32x4 acc[4][2];
  #pragma unroll
  for (int m = 0; m < 4; m++)
    #pragma unroll
    for (int j = 0; j < 2; j++)
      acc[m][j] = (f32x4){0.f, 0.f, 0.f, 0.f};

  int arow = tid >> 2, aq = tid & 3;     // A: 8 floats -> hi/lo 16B each
  int bcol = tid >> 1, bh2 = tid & 1;    // B: 32B per array

  for (int k0 = 0; k0 < KP; k0 += 32) {
    __syncthreads();
    // ---- stage A (convert fp32 -> bf16 hi/lo in-register) ----
    {
      int kbase = k0 + aq * 8;
      const float* xr = X + (size_t)idxs[arow] * D_IN;
      float v[8];
      if (kbase + 8 <= D_IN) {
        float4 p0 = *(const float4*)(xr + kbase);
        float4 p1 = *(const float4*)(xr + kbase + 4);
        v[0]=p0.x; v[1]=p0.y; v[2]=p0.z; v[3]=p0.w;
        v[4]=p1.x; v[5]=p1.y; v[6]=p1.z; v[7]=p1.w;
      } else {
        #pragma unroll
        for (int q = 0; q < 8; q++) v[q] = (kbase + q < D_IN) ? xr[kbase + q] : 0.f;
      }
      uint32_t ph[4], pl[4];
      #pragma unroll
      for (int q = 0; q < 4; q++) {
        ushort h0 = f2bf_rne(v[2*q]),   h1 = f2bf_rne(v[2*q+1]);
        ushort l0 = f2bf_rne(v[2*q]   - bf2f(h0));
        ushort l1 = f2bf_rne(v[2*q+1] - bf2f(h1));
        ph[q] = (uint32_t)h0 | ((uint32_t)h1 << 16);
        pl[q] = (uint32_t)l0 | ((uint32_t)l1 << 16);
      }
      *(uint4*)&Ah[arow][aq*8] = make_uint4(ph[0], ph[1], ph[2], ph[3]);
      *(uint4*)&Al[arow][aq*8] = make_uint4(pl[0], pl[1], pl[2], pl[3]);
    }
    // ---- stage B (already bf16 split, transposed [c][k]) ----
    {
      int boff = bh2 * 16;
      const uint4* sh = (const uint4*)(Wthi + (size_t)bcol * KP + k0 + boff);
      const uint4* sl = (const uint4*)(Wtlo + (size_t)bcol * KP + k0 + boff);
      uint4 h0 = sh[0], h1 = sh[1], l0 = sl[0], l1 = sl[1];
      *(uint4*)&Bh[bcol][boff]     = h0;
      *(uint4*)&Bh[bcol][boff + 8] = h1;
      *(uint4*)&Bl[bcol][boff]     = l0;
      *(uint4*)&Bl[bcol][boff + 8] = l1;
    }
    __syncthreads();
    // ---- compute ----
    bf16x8 bhf[2], blf[2];
    #pragma unroll
    for (int j = 0; j < 2; j++) {
      int n = (2 * wave + j) * 16 + ln;
      bhf[j] = *(bf16x8*)&Bh[n][kg * 8];
      blf[j] = *(bf16x8*)&Bl[n][kg * 8];
    }
    #pragma unroll
    for (int m = 0; m < 4; m++) {
      bf16x8 ah = *(bf16x8*)&Ah[m * 16 + ln][kg * 8];
      bf16x8 al = *(bf16x8*)&Al[m * 16 + ln][kg * 8];
      #pragma unroll
      for (int j = 0; j < 2; j++) {
        acc[m][j] = __builtin_amdgcn_mfma_f32_16x16x32_bf16(ah, bhf[j], acc[m][j], 0, 0, 0);
        acc[m][j] = __builtin_amdgcn_mfma_f32_16x16x32_bf16(ah, blf[j], acc[m][j], 0, 0, 0);
        acc[m][j] = __builtin_amdgcn_mfma_f32_16x16x32_bf16(al, bhf[j], acc[m][j], 0, 0, 0);
      }
    }
  }
  // ---- epilogue: bias + sigmoid, C/D layout col=lane&15, row=(lane>>4)*4+reg ----
  #pragma unroll
  for (int j = 0; j < 2; j++) {
    int col = (2 * wave + j) * 16 + ln;
    float bias = (col < NC) ? br[col] : 0.f;
    #pragma unroll
    for (int m = 0; m < 4; m++) {
      #pragma unroll
      for (int r = 0; r < 4; r++) {
        int row = row0 + m * 16 + kg * 4 + r;
        if (row < bs) {
          float z = acc[m][j][r] + bias;
          hbuf[(size_t)row * NCP + col] = 1.f / (1.f + expf(-z));
        }
      }
    }
  }
}

__global__ __launch_bounds__(256) void k_reduce_v(const float* __restrict__ hbuf,
    const float* __restrict__ ek, Hdr* h, int bs) {
  int c = blockIdx.x;
  int tid = threadIdx.x;
  float den = 0.f, num[10];
  #pragma unroll
  for (int j = 0; j < 10; j++) num[j] = 0.f;
  for (int i = tid; i < bs; i += 256) {
    float hv = hbuf[(size_t)i * NCP + c];
    den += hv * hv;
    const float* e = ek + (size_t)i * 10;
    #pragma unroll
    for (int j = 0; j < 10; j++) num[j] += hv * e[j];
  }
  __shared__ float red[256][11];
  red[tid][0] = den;
  #pragma unroll
  for (int j = 0; j < 10; j++) red[tid][1 + j] = num[j];
  __syncthreads();
  for (int s = 128; s > 0; s >>= 1) {
    if (tid < s) {
      #pragma unroll
      for (int q = 0; q < 11; q++) red[tid][q] += red[tid + s][q];
    }
    __syncthreads();
  }
  if (tid == 0) {
    h->den[c] = red[0][0];
    #pragma unroll
    for (int j = 0; j < 10; j++) h->num[c * 10 + j] = red[0][1 + j];
  }
}

__global__ void k_select(Hdr* h, const float* __restrict__ br, float* __restrict__ out_b, int k) {
  if (threadIdx.x != 0 || blockIdx.x != 0) return;
  float best = -1.f; int bi = 0;
  for (int c = 0; c < NC; c++) {
    float s = 0.f;
    for (int j = 0; j < 10; j++) { float n = h->num[c * 10 + j]; s += n * n; }
    float v = s / (h->den[c] * 10.f);
    if (v > best) { best = v; bi = c; }
  }
  h->best = bi;
  h->bsel = br[k * NC + bi];
  out_b[k] = h->bsel;
}

__global__ __launch_bounds__(256) void k_wcol(const Hdr* __restrict__ h,
    const float* __restrict__ Wr, float* __restrict__ wcol, float* __restrict__ outW, int k) {
  int d = blockIdx.x * 256 + threadIdx.x;
  if (d >= D_IN) return;
  float v = Wr[(size_t)d * NCP + h->best];
  wcol[d] = v;
  outW[d * 12 + k] = v;
}

__global__ __launch_bounds__(256) void k_hc(const float* __restrict__ X,
    const Hdr* __restrict__ h, const float* __restrict__ wcol,
    float* __restrict__ H, float* __restrict__ hc, int k) {
  int lane = threadIdx.x & 63;
  int row = blockIdx.x * 4 + (threadIdx.x >> 6);
  if (row >= N_ROWS) return;
  const float* xp = X + (size_t)row * D_IN;
  float acc = 0.f;
  for (int d = lane; d < D_IN; d += 64) acc += xp[d] * wcol[d];
  for (int o = 32; o > 0; o >>= 1) acc += __shfl_down(acc, o, 64);
  if (lane == 0) {
    float hv = 1.f / (1.f + expf(-(acc + h->bsel)));
    H[(size_t)row * 12 + k] = hv;
    hc[row] = hv;
  }
}

__global__ __launch_bounds__(256) void k_dotQ(const float* __restrict__ Qcm,
    const float* __restrict__ vec, float* __restrict__ dst) {
  int j = blockIdx.x;
  const float* q = Qcm + (size_t)j * N_ROWS;
  float a = 0.f;
  for (int i = threadIdx.x; i < N_ROWS; i += 256) a += q[i] * vec[i];
  __shared__ float red[256];
  red[threadIdx.x] = a;
  __syncthreads();
  for (int s = 128; s > 0; s >>= 1) {
    if (threadIdx.x < s) red[threadIdx.x] += red[threadIdx.x + s];
    __syncthreads();
  }
  if (threadIdx.x == 0) dst[j] = red[0];
}

__global__ __launch_bounds__(256) void k_sub(float* __restrict__ Qcm,
    const float* __restrict__ basev, const float* __restrict__ coef,
    float* __restrict__ partials, int k) {
  int i = blockIdx.x * 256 + threadIdx.x;
  float t = 0.f;
  if (i < N_ROWS) {
    t = basev[i];
    for (int j = 0; j < k; j++) t -= Qcm[(size_t)j * N_ROWS + i] * coef[j];
    Qcm[(size_t)k * N_ROWS + i] = t;
  }
  __shared__ float red[256];
  red[threadIdx.x] = t * t;
  __syncthreads();
  for (int s = 128; s > 0; s >>= 1) {
    if (threadIdx.x < s) red[threadIdx.x] += red[threadIdx.x + s];
    __syncthreads();
  }
  if (threadIdx.x == 0) partials[blockIdx.x] = red[0];
}

__global__ void k_r2(Hdr* h, const float* __restrict__ partials, int k) {
  int tid = threadIdx.x;
  if (tid == 0) {
    float s = 0.f;
    for (int b = 0; b < SORT_BLOCKS; b++) s += partials[b];
    float r2 = sqrtf(s);
    h->r2 = r2;
    h->inv_r2 = 1.f / r2;
    h->R[k * 12 + k] = r2;
  }
  if (tid < k) h->R[tid * 12 + k] = h->r1[tid] + h->r1b[tid];
}

__global__ __launch_bounds__(256) void k_qt(Hdr* h, const float* __restrict__ Qk,
    const float* __restrict__ Y, int k) {
  int j = blockIdx.x;
  float a = 0.f;
  for (int i = threadIdx.x; i < N_ROWS; i += 256) a += Qk[i] * Y[(size_t)i * 10 + j];
  __shared__ float red[256];
  red[threadIdx.x] = a;
  __syncthreads();
  for (int s = 128; s > 0; s >>= 1) {
    if (threadIdx.x < s) red[threadIdx.x] += red[threadIdx.x + s];
    __syncthreads();
  }
  if (threadIdx.x == 0) h->QT[k * 10 + j] = red[0] * h->inv_r2;
}

__global__ __launch_bounds__(256) void k_qnorm(float* __restrict__ Qk, const Hdr* __restrict__ h) {
  int i = blockIdx.x * 256 + threadIdx.x;
  if (i < N_ROWS) Qk[i] *= h->inv_r2;
}

__global__ void k_backsub(Hdr* h, float* __restrict__ out_beta, int k) {
  int j = threadIdx.x;
  if (j >= 10 || blockIdx.x != 0) return;
  for (int i = k; i >= 0; i--) {
    float t = h->QT[i * 10 + j];
    for (int m = i + 1; m <= k; m++) t -= h->R[i * 12 + m] * h->beta[m * 10 + j];
    t /= h->R[i * 12 + i];
    h->beta[i * 10 + j] = t;
    out_beta[i * 10 + j] = t;
  }
}

__global__ __launch_bounds__(256) void k_y(const Hdr* __restrict__ h,
    const float* __restrict__ H, float* __restrict__ y, int k) {
  __shared__ float sb[120];
  if (threadIdx.x < 120) sb[threadIdx.x] = h->beta[threadIdx.x];
  __syncthreads();
  int i = blockIdx.x * 256 + threadIdx.x;
  if (i >= N_ROWS) return;
  float hr[12];
  for (int m = 0; m <= k; m++) hr[m] = H[(size_t)i * 12 + m];
  #pragma unroll
  for (int j = 0; j < 10; j++) {
    float a = 0.f;
    for (int m = 0; m <= k; m++) a += hr[m] * sb[m * 10 + j];
    y[(size_t)i * 10 + j] = a;
  }
}

static inline int cdiv(int a, int b) { return (a + b - 1) / b; }

extern "C" void kernel_launch(void* const* d_in, const int* in_sizes, int n_in,
                              void* d_out, int out_size, void* d_ws, size_t ws_size,
                              hipStream_t stream) {
  const float* X = (const float*)d_in[0];
  const float* Y = (const float*)d_in[1];
  float* out = (float*)d_out;
  float* outW = out;             // 784*12
  float* outB = out + 9408;      // 12
  float* outBeta = out + 9420;   // 12*10

  char* base = (char*)d_ws;
  Hdr* hdr = (Hdr*)base;
  float* r1p  = (float*)(base + offsetof(Hdr, r1));
  float* r1bp = (float*)(base + offsetof(Hdr, r1b));

  size_t off = 16384;
  auto nxt = [&](size_t bytes) -> void* {
    void* p = base + off;
    off += (bytes + 255) & ~(size_t)255;
    return p;
  };
  uint32_t* keysA = (uint32_t*)nxt((size_t)NSEG * SEG * 4);
  uint32_t* keysB = (uint32_t*)nxt((size_t)NSEG * SEG * 4);
  int* valsA = (int*)nxt((size_t)NSEG * SEG * 4);
  int* valsB = (int*)nxt((size_t)NSEG * SEG * 4);
  uint32_t* hs = (uint32_t*)nxt((size_t)NSEG * SORT_BLOCKS * 256 * 4);
  float* WrAll = (float*)nxt((size_t)NSEG * D_IN * NCP * 4);
  short* WthiAll = (short*)nxt((size_t)NSEG * NCP * KP * 2);
  short* WtloAll = (short*)nxt((size_t)NSEG * NCP * KP * 2);
  float* brAll = (float*)nxt((size_t)NSEG * NC * 4);
  float* wcol = (float*)nxt((size_t)D_IN * 4);
  float* hbuf = (float*)nxt((size_t)27840 * NCP * 4);
  float* ekbuf = (float*)nxt((size_t)27840 * 10 * 4);
  float* Qcm = (float*)nxt((size_t)12 * N_ROWS * 4);
  float* Hbuf = (float*)nxt((size_t)N_ROWS * 12 * 4);
  float* hcbuf = (float*)nxt((size_t)N_ROWS * 4);
  float* ybuf = (float*)nxt((size_t)N_ROWS * 10 * 4);
  float* partials = (float*)nxt(128 * 4);

  // 1. RNG key chain
  k_rng_chain<<<1, 64, 0, stream>>>(hdr);

  // 2. permutations: 2 rounds x 4 radix passes
  const int keygrid = cdiv(NSEG * SEG, 256);
  const int sortgrid = NSEG * SORT_BLOCKS;
  for (int round = 0; round < 2; round++) {
    k_sortkeys<<<keygrid, 256, 0, stream>>>(hdr, keysA, valsA, round);
    for (int pass = 0; pass < 4; pass++) {
      uint32_t* ik = (pass & 1) ? keysB : keysA;
      uint32_t* ok = (pass & 1) ? keysA : keysB;
      int* iv = (pass & 1) ? valsB : valsA;
      int* ov = (pass & 1) ? valsA : valsB;
      k_hist<<<sortgrid, 256, 0, stream>>>(ik, hs, 8 * pass);
      k_scan<<<NSEG, 256, 0, stream>>>(hs);
      k_scatter<<<sortgrid, 256, 0, stream>>>(ik, iv, ok, ov, hs, 8 * pass);
    }
  }

  // 3. candidate weights (fp32 + transposed bf16 hi/lo)
  k_gen<<<cdiv(NSEG * NCP * KP, 256), 256, 0, stream>>>(hdr, WrAll, WthiAll, WtloAll);
  k_genb<<<cdiv(NSEG * NC, 256), 256, 0, stream>>>(hdr, brAll);

  // 4. sequential training loop
  for (int k = 0; k < 12; k++) {
    int bs = 4000 + 2166 * k;
    const int* perm = valsA + (size_t)k * SEG;
    const short* Wthi = WthiAll + (size_t)k * NCP * KP;
    const short* Wtlo = WtloAll + (size_t)k * NCP * KP;
    const float* brk = brAll + (size_t)k * NC;

    k_ek<<<cdiv(bs, 256), 256, 0, stream>>>(Y, ybuf, perm, ekbuf, hdr, k, bs);
    k_batch_mfma<<<cdiv(bs, 64), 256, 0, stream>>>(X, Wthi, Wtlo, brk, perm, hbuf, bs);
    k_reduce_v<<<NC, 256, 0, stream>>>(hbuf, ekbuf, hdr, bs);
    k_select<<<1, 64, 0, stream>>>(hdr, brAll, outB, k);
    k_wcol<<<cdiv(D_IN, 256), 256, 0, stream>>>(hdr, WrAll + (size_t)k * D_IN * NCP, wcol, outW, k);
    k_hc<<<N_ROWS / 4, 256, 0, stream>>>(X, hdr, wcol, Hbuf, hcbuf, k);

    if (k > 0) k_dotQ<<<k, 256, 0, stream>>>(Qcm, hcbuf, r1p);
    k_sub<<<SORT_BLOCKS, 256, 0, stream>>>(Qcm, hcbuf, r1p, partials, k);
    if (k == 1 || k == 2) {  // reorthogonalize (emulates inv/Householder branches)
      k_dotQ<<<k, 256, 0, stream>>>(Qcm, Qcm + (size_t)k * N_ROWS, r1bp);
      k_sub<<<SORT_BLOCKS, 256, 0, stream>>>(Qcm, Qcm + (size_t)k * N_ROWS, r1bp, partials, k);
    }
    k_r2<<<1, 64, 0, stream>>>(hdr, partials, k);
    k_qt<<<10, 256, 0, stream>>>(hdr, Qcm + (size_t)k * N_ROWS, Y, k);
    k_qnorm<<<SORT_BLOCKS, 256, 0, stream>>>(Qcm + (size_t)k * N_ROWS, hdr);
    k_backsub<<<1, 64, 0, stream>>>(hdr, outBeta, k);
    k_y<<<SORT_BLOCKS, 256, 0, stream>>>(hdr, Hbuf, ybuf, k);
  }
}